// Round 2
// baseline (291.893 us; speedup 1.0000x reference)
//
#include <hip/hip_runtime.h>

#define Bn 16
#define Nn 256
#define Tn 96
#define Hn 128
#define EPSf 1e-5f

typedef float v4f __attribute__((ext_vector_type(4)));

// ---------------------------------------------------------------------------
// Precompute kernel: builds three small matrices into workspace.
//   M [Tn x Hn]  = Wp @ W1                       (W1 = Wf[0:128])
//   E [Nn x Hn]  = node_emb @ W2 + bp @ W1       (W2 = Wf[128:256])
//   Ct[Tn x Hn]  = time_emb @ W3 + bf            (W3 = Wf[256:384])
// grid = Tn + Nn + Tn = 448 blocks, block = 128 threads (thread k = out col).
// ---------------------------------------------------------------------------
__global__ __launch_bounds__(128) void precompute_kernel(
    const float* __restrict__ Wp, const float* __restrict__ bp,
    const float* __restrict__ Wf, const float* __restrict__ bf,
    const float* __restrict__ node_emb, const float* __restrict__ time_emb,
    float* __restrict__ M, float* __restrict__ E, float* __restrict__ Ct) {
  __shared__ float row[Hn];
  const int k = threadIdx.x;
  const int bid = blockIdx.x;
  if (bid < Tn) {
    const int t = bid;
    row[k] = Wp[t * Hn + k];
    __syncthreads();
    float acc = 0.f;
#pragma unroll 8
    for (int h = 0; h < Hn; ++h) acc = fmaf(row[h], Wf[h * Hn + k], acc);
    M[t * Hn + k] = acc;
  } else if (bid < Tn + Nn) {
    const int n = bid - Tn;
    row[k] = node_emb[n * Hn + k];
    __syncthreads();
    float acc = 0.f;
#pragma unroll 8
    for (int h = 0; h < Hn; ++h) acc = fmaf(row[h], Wf[(Hn + h) * Hn + k], acc);
    __syncthreads();
    row[k] = bp[k];
    __syncthreads();
#pragma unroll 8
    for (int h = 0; h < Hn; ++h) acc = fmaf(row[h], Wf[h * Hn + k], acc);
    E[n * Hn + k] = acc;
  } else {
    const int t = bid - Tn - Nn;
    row[k] = time_emb[t * Hn + k];
    __syncthreads();
    float acc = bf[k];
#pragma unroll 8
    for (int h = 0; h < Hn; ++h) acc = fmaf(row[h], Wf[(2 * Hn + h) * Hn + k], acc);
    Ct[t * Hn + k] = acc;
  }
}

// ---------------------------------------------------------------------------
// Projection kernel: A[bn][k] = sum_t x[bn][t] * M[t][k] + E[n][k].
// 2 rows per block (256 threads = 2 x 128 columns). grid = Bn*Nn/2 = 2048.
// ---------------------------------------------------------------------------
__global__ __launch_bounds__(256) void proj_kernel(
    const float* __restrict__ x, const float* __restrict__ M,
    const float* __restrict__ E, float* __restrict__ A) {
  __shared__ float xs[2][Tn];
  const int tid = threadIdx.x;
  const int row0 = blockIdx.x * 2;
  if (tid < 2 * Tn) {
    const int rr = tid >= Tn;
    xs[rr][tid - rr * Tn] = x[row0 * Tn + tid];
  }
  __syncthreads();
  const int half = tid >> 7;  // 0,1
  const int k = tid & 127;
  const int bn = row0 + half;
  const int n = bn & (Nn - 1);
  float acc = E[n * Hn + k];
#pragma unroll 8
  for (int t = 0; t < Tn; ++t) acc = fmaf(xs[half][t], M[t * Hn + k], acc);
  A[bn * Hn + k] = acc;
}

// ---------------------------------------------------------------------------
// 16-lane reduction via DPP (VALU pipe, no LDS, no lgkmcnt waits).
// Summation tree is identical to the previous xor1/2/4/8 butterfly:
//   quad_perm(1,0,3,2) = lane^1 ; quad_perm(2,3,0,1) = lane^2 ;
//   row_ror:4 pairs adjacent quads ; row_ror:8 combines quad-pairs.
// ---------------------------------------------------------------------------
template <int CTRL>
__device__ __forceinline__ float dpp_add(float v) {
  return v + __int_as_float(__builtin_amdgcn_update_dpp(
                 0, __float_as_int(v), CTRL, 0xF, 0xF, true));
}
__device__ __forceinline__ float row16_sum(float v) {
  v = dpp_add<0xB1>(v);   // quad_perm [1,0,3,2]  (xor 1)
  v = dpp_add<0x4E>(v);   // quad_perm [2,3,0,1]  (xor 2)
  v = dpp_add<0x124>(v);  // row_ror:4
  v = dpp_add<0x128>(v);  // row_ror:8
  return v;
}

// Shared per-row epilogue: relu + layernorm + affine + nontemporal store.
__device__ __forceinline__ void ln_row_store(
    const float4 a0, const float4 a1, const float4 g0, const float4 g1,
    const float4 q0, const float4 q1, const float* __restrict__ ct_row,
    float* __restrict__ op) {
  const float4 c0 = *(const float4*)ct_row;
  const float4 c1 = *(const float4*)(ct_row + 4);
  const float h0 = fmaxf(a0.x + c0.x, 0.f);
  const float h1 = fmaxf(a0.y + c0.y, 0.f);
  const float h2 = fmaxf(a0.z + c0.z, 0.f);
  const float h3 = fmaxf(a0.w + c0.w, 0.f);
  const float h4 = fmaxf(a1.x + c1.x, 0.f);
  const float h5 = fmaxf(a1.y + c1.y, 0.f);
  const float h6 = fmaxf(a1.z + c1.z, 0.f);
  const float h7 = fmaxf(a1.w + c1.w, 0.f);

  float s = ((h0 + h1) + (h2 + h3)) + ((h4 + h5) + (h6 + h7));
  float ss = h0 * h0;
  ss = fmaf(h1, h1, ss); ss = fmaf(h2, h2, ss); ss = fmaf(h3, h3, ss);
  ss = fmaf(h4, h4, ss); ss = fmaf(h5, h5, ss); ss = fmaf(h6, h6, ss);
  ss = fmaf(h7, h7, ss);

  s = row16_sum(s);
  ss = row16_sum(ss);

  const float inv128 = 1.f / 128.f;
  const float mean = s * inv128;
  const float var = fmaf(-mean, mean, ss * inv128);
  const float inv = rsqrtf(var + EPSf);

  v4f o0, o1;
  o0.x = fmaf((h0 - mean) * inv, g0.x, q0.x);
  o0.y = fmaf((h1 - mean) * inv, g0.y, q0.y);
  o0.z = fmaf((h2 - mean) * inv, g0.z, q0.z);
  o0.w = fmaf((h3 - mean) * inv, g0.w, q0.w);
  o1.x = fmaf((h4 - mean) * inv, g1.x, q1.x);
  o1.y = fmaf((h5 - mean) * inv, g1.y, q1.y);
  o1.z = fmaf((h6 - mean) * inv, g1.z, q1.z);
  o1.w = fmaf((h7 - mean) * inv, g1.w, q1.w);

  __builtin_nontemporal_store(o0, (v4f*)op);
  __builtin_nontemporal_store(o1, (v4f*)(op + 4));
}

// ---------------------------------------------------------------------------
// Streaming kernel: one block per (b,n). No LDS, no barriers. Lane owns 8
// columns; 16 lanes per t-row; wave handles 4 t-rows/iter; 6 iters.
// ---------------------------------------------------------------------------
__global__ __launch_bounds__(256) void stream_kernel(
    const float* __restrict__ A, const float* __restrict__ Ct,
    const float* __restrict__ gamma, const float* __restrict__ beta,
    float* __restrict__ out) {
  const int bn = blockIdx.x;
  const int tid = threadIdx.x;
  const int wave = tid >> 6;
  const int lane = tid & 63;
  const int r = lane >> 4;
  const int cg = lane & 15;
  const int cb = cg * 8;

  const float4 a0 = *(const float4*)&A[bn * Hn + cb];
  const float4 a1 = *(const float4*)&A[bn * Hn + cb + 4];
  const float4 g0 = *(const float4*)&gamma[cb];
  const float4 g1 = *(const float4*)&gamma[cb + 4];
  const float4 q0 = *(const float4*)&beta[cb];
  const float4 q1 = *(const float4*)&beta[cb + 4];

  const int tbase = wave * 4 + r;
  float* outb = out + (size_t)bn * Tn * Hn + cb;
  const float* ctb = Ct + cb;

#pragma unroll
  for (int i = 0; i < Tn / 16; ++i) {
    const int t = i * 16 + tbase;
    ln_row_store(a0, a1, g0, g1, q0, q1, ctb + t * Hn, outb + (size_t)t * Hn);
  }
}

// ---------------------------------------------------------------------------
// Fused fallback (used only if workspace is too small for A): original
// structure, but with DPP reduction + nontemporal stores.
// ---------------------------------------------------------------------------
__global__ __launch_bounds__(256) void fused_kernel(
    const float* __restrict__ x, const float* __restrict__ M,
    const float* __restrict__ E, const float* __restrict__ Ct,
    const float* __restrict__ gamma, const float* __restrict__ beta,
    float* __restrict__ out) {
  const int bn = blockIdx.x;
  const int n = bn & (Nn - 1);
  __shared__ float xs[Tn];
  __shared__ __align__(16) float as[Hn];
  const int tid = threadIdx.x;

  if (tid < Tn) xs[tid] = x[bn * Tn + tid];
  __syncthreads();
  if (tid < Hn) {
    float acc = E[n * Hn + tid];
#pragma unroll 8
    for (int t = 0; t < Tn; ++t) acc = fmaf(xs[t], M[t * Hn + tid], acc);
    as[tid] = acc;
  }
  __syncthreads();

  const int wave = tid >> 6;
  const int lane = tid & 63;
  const int r = lane >> 4;
  const int cg = lane & 15;
  const int cb = cg * 8;

  const float4 a0 = *(const float4*)&as[cb];
  const float4 a1 = *(const float4*)&as[cb + 4];
  const float4 g0 = *(const float4*)&gamma[cb];
  const float4 g1 = *(const float4*)&gamma[cb + 4];
  const float4 q0 = *(const float4*)&beta[cb];
  const float4 q1 = *(const float4*)&beta[cb + 4];

  const int tbase = wave * 4 + r;
  float* outb = out + (size_t)bn * Tn * Hn + cb;
  const float* ctb = Ct + cb;

#pragma unroll
  for (int i = 0; i < Tn / 16; ++i) {
    const int t = i * 16 + tbase;
    ln_row_store(a0, a1, g0, g1, q0, q1, ctb + t * Hn, outb + (size_t)t * Hn);
  }
}

extern "C" void kernel_launch(void* const* d_in, const int* in_sizes, int n_in,
                              void* d_out, int out_size, void* d_ws, size_t ws_size,
                              hipStream_t stream) {
  const float* x        = (const float*)d_in[0];
  const float* Wp       = (const float*)d_in[1];
  const float* bp       = (const float*)d_in[2];
  const float* Wf       = (const float*)d_in[3];
  const float* bf       = (const float*)d_in[4];
  const float* gamma    = (const float*)d_in[5];
  const float* beta     = (const float*)d_in[6];
  const float* node_emb = (const float*)d_in[7];
  const float* time_emb = (const float*)d_in[8];
  float* out = (float*)d_out;

  // Workspace layout (floats): M[96*128] | E[256*128] | Ct[96*128] | A[4096*128]
  float* ws = (float*)d_ws;
  float* M  = ws;
  float* E  = ws + Tn * Hn;
  float* Ct = ws + Tn * Hn + Nn * Hn;
  float* A  = ws + Tn * Hn + Nn * Hn + Tn * Hn;

  const size_t need =
      (size_t)(Tn * Hn + Nn * Hn + Tn * Hn + Bn * Nn * Hn) * sizeof(float);

  precompute_kernel<<<Tn + Nn + Tn, 128, 0, stream>>>(Wp, bp, Wf, bf, node_emb,
                                                      time_emb, M, E, Ct);
  if (ws_size >= need) {
    proj_kernel<<<Bn * Nn / 2, 256, 0, stream>>>(x, M, E, A);
    stream_kernel<<<Bn * Nn, 256, 0, stream>>>(A, Ct, gamma, beta, out);
  } else {
    fused_kernel<<<Bn * Nn, 256, 0, stream>>>(x, M, E, Ct, gamma, beta, out);
  }
}

// Round 3
// 230.519 us; speedup vs baseline: 1.2662x; 1.2662x over previous
//
#include <hip/hip_runtime.h>

#define Bn 16
#define Nn 256
#define Tn 96
#define Hn 128
#define EPSf 1e-5f

// ---------------------------------------------------------------------------
// Precompute kernel: builds three small matrices into workspace.
//   M [Tn x Hn]  = Wp @ W1                       (W1 = Wf[0:128])
//   E [Nn x Hn]  = node_emb @ W2 + bp @ W1       (W2 = Wf[128:256])
//   Ct[Tn x Hn]  = time_emb @ W3 + bf            (W3 = Wf[256:384])
// grid = Tn + Nn + Tn = 448 blocks, block = 128 threads (thread k = out col).
// ---------------------------------------------------------------------------
__global__ __launch_bounds__(128) void precompute_kernel(
    const float* __restrict__ Wp, const float* __restrict__ bp,
    const float* __restrict__ Wf, const float* __restrict__ bf,
    const float* __restrict__ node_emb, const float* __restrict__ time_emb,
    float* __restrict__ M, float* __restrict__ E, float* __restrict__ Ct) {
  __shared__ float row[Hn];
  const int k = threadIdx.x;
  const int bid = blockIdx.x;
  if (bid < Tn) {
    const int t = bid;
    row[k] = Wp[t * Hn + k];
    __syncthreads();
    float acc = 0.f;
#pragma unroll 8
    for (int h = 0; h < Hn; ++h) acc = fmaf(row[h], Wf[h * Hn + k], acc);
    M[t * Hn + k] = acc;
  } else if (bid < Tn + Nn) {
    const int n = bid - Tn;
    row[k] = node_emb[n * Hn + k];
    __syncthreads();
    float acc = 0.f;
#pragma unroll 8
    for (int h = 0; h < Hn; ++h) acc = fmaf(row[h], Wf[(Hn + h) * Hn + k], acc);
    __syncthreads();
    row[k] = bp[k];
    __syncthreads();
#pragma unroll 8
    for (int h = 0; h < Hn; ++h) acc = fmaf(row[h], Wf[h * Hn + k], acc);
    E[n * Hn + k] = acc;
  } else {
    const int t = bid - Tn - Nn;
    row[k] = time_emb[t * Hn + k];
    __syncthreads();
    float acc = bf[k];
#pragma unroll 8
    for (int h = 0; h < Hn; ++h) acc = fmaf(row[h], Wf[(2 * Hn + h) * Hn + k], acc);
    Ct[t * Hn + k] = acc;
  }
}

// ---------------------------------------------------------------------------
// Projection kernel: A[bn][k] = sum_t x[bn][t] * M[t][k] + E[n][k].
// 2 rows per block (256 threads = 2 x 128 columns). grid = Bn*Nn/2 = 2048.
// ---------------------------------------------------------------------------
__global__ __launch_bounds__(256) void proj_kernel(
    const float* __restrict__ x, const float* __restrict__ M,
    const float* __restrict__ E, float* __restrict__ A) {
  __shared__ float xs[2][Tn];
  const int tid = threadIdx.x;
  const int row0 = blockIdx.x * 2;
  if (tid < 2 * Tn) {
    const int rr = tid >= Tn;
    xs[rr][tid - rr * Tn] = x[row0 * Tn + tid];
  }
  __syncthreads();
  const int half = tid >> 7;  // 0,1
  const int k = tid & 127;
  const int bn = row0 + half;
  const int n = bn & (Nn - 1);
  float acc = E[n * Hn + k];
#pragma unroll 8
  for (int t = 0; t < Tn; ++t) acc = fmaf(xs[half][t], M[t * Hn + k], acc);
  A[bn * Hn + k] = acc;
}

// ---------------------------------------------------------------------------
// 16-lane reduction via DPP (VALU pipe, no LDS, no lgkmcnt waits).
// Summation tree identical to the original xor1/2/4/8 butterfly:
//   quad_perm(1,0,3,2) = lane^1 ; quad_perm(2,3,0,1) = lane^2 ;
//   row_ror:4 pairs adjacent quads ; row_ror:8 combines quad-pairs.
// ---------------------------------------------------------------------------
template <int CTRL>
__device__ __forceinline__ float dpp_add(float v) {
  return v + __int_as_float(__builtin_amdgcn_update_dpp(
                 0, __float_as_int(v), CTRL, 0xF, 0xF, true));
}
__device__ __forceinline__ float row16_sum(float v) {
  v = dpp_add<0xB1>(v);   // quad_perm [1,0,3,2]  (xor 1)
  v = dpp_add<0x4E>(v);   // quad_perm [2,3,0,1]  (xor 2)
  v = dpp_add<0x124>(v);  // row_ror:4
  v = dpp_add<0x128>(v);  // row_ror:8
  return v;
}

// Shared per-row epilogue: relu + layernorm + affine + store.
// Lane cg owns cols [cg*4, cg*4+4) (ptrs *0) and [64+cg*4, ...) (ptrs *1), so
// each 16-lane store instruction covers a CONTIGUOUS 256 B run of the row.
// Normal cached stores: L2 merges and writes back full lines (nt regressed —
// partial-line streaming writes forced DRAM read-modify-write, R2 post-mortem).
__device__ __forceinline__ void ln_row_store(
    const float4 a0, const float4 a1, const float4 g0, const float4 g1,
    const float4 q0, const float4 q1, const float* __restrict__ ct0,
    const float* __restrict__ ct1, float* __restrict__ op0,
    float* __restrict__ op1) {
  const float4 c0 = *(const float4*)ct0;
  const float4 c1 = *(const float4*)ct1;
  const float h0 = fmaxf(a0.x + c0.x, 0.f);
  const float h1 = fmaxf(a0.y + c0.y, 0.f);
  const float h2 = fmaxf(a0.z + c0.z, 0.f);
  const float h3 = fmaxf(a0.w + c0.w, 0.f);
  const float h4 = fmaxf(a1.x + c1.x, 0.f);
  const float h5 = fmaxf(a1.y + c1.y, 0.f);
  const float h6 = fmaxf(a1.z + c1.z, 0.f);
  const float h7 = fmaxf(a1.w + c1.w, 0.f);

  float s = ((h0 + h1) + (h2 + h3)) + ((h4 + h5) + (h6 + h7));
  float ss = h0 * h0;
  ss = fmaf(h1, h1, ss); ss = fmaf(h2, h2, ss); ss = fmaf(h3, h3, ss);
  ss = fmaf(h4, h4, ss); ss = fmaf(h5, h5, ss); ss = fmaf(h6, h6, ss);
  ss = fmaf(h7, h7, ss);

  s = row16_sum(s);
  ss = row16_sum(ss);

  const float inv128 = 1.f / 128.f;
  const float mean = s * inv128;
  const float var = fmaf(-mean, mean, ss * inv128);
  const float inv = rsqrtf(var + EPSf);

  float4 o0, o1;
  o0.x = fmaf((h0 - mean) * inv, g0.x, q0.x);
  o0.y = fmaf((h1 - mean) * inv, g0.y, q0.y);
  o0.z = fmaf((h2 - mean) * inv, g0.z, q0.z);
  o0.w = fmaf((h3 - mean) * inv, g0.w, q0.w);
  o1.x = fmaf((h4 - mean) * inv, g1.x, q1.x);
  o1.y = fmaf((h5 - mean) * inv, g1.y, q1.y);
  o1.z = fmaf((h6 - mean) * inv, g1.z, q1.z);
  o1.w = fmaf((h7 - mean) * inv, g1.w, q1.w);

  *(float4*)op0 = o0;
  *(float4*)op1 = o1;
}

// ---------------------------------------------------------------------------
// Streaming kernel: one block per (b,n). No LDS, no barriers. Lane owns 8
// columns (two contiguous float4 half-row slots); 16 lanes per t-row; a wave
// handles 4 t-rows per iteration; 6 iterations.
// ---------------------------------------------------------------------------
__global__ __launch_bounds__(256) void stream_kernel(
    const float* __restrict__ A, const float* __restrict__ Ct,
    const float* __restrict__ gamma, const float* __restrict__ beta,
    float* __restrict__ out) {
  const int bn = blockIdx.x;
  const int tid = threadIdx.x;
  const int wave = tid >> 6;
  const int lane = tid & 63;
  const int r = lane >> 4;
  const int cg = lane & 15;
  const int cb0 = cg * 4;        // cols [cb0, cb0+4)
  const int cb1 = 64 + cg * 4;   // cols [cb1, cb1+4)

  const float4 a0 = *(const float4*)&A[bn * Hn + cb0];
  const float4 a1 = *(const float4*)&A[bn * Hn + cb1];
  const float4 g0 = *(const float4*)&gamma[cb0];
  const float4 g1 = *(const float4*)&gamma[cb1];
  const float4 q0 = *(const float4*)&beta[cb0];
  const float4 q1 = *(const float4*)&beta[cb1];

  const int tbase = wave * 4 + r;
  float* outr = out + (size_t)bn * Tn * Hn;
  const float* ct0 = Ct + cb0;
  const float* ct1 = Ct + cb1;

#pragma unroll
  for (int i = 0; i < Tn / 16; ++i) {
    const int t = i * 16 + tbase;
    ln_row_store(a0, a1, g0, g1, q0, q1, ct0 + t * Hn, ct1 + t * Hn,
                 outr + (size_t)t * Hn + cb0, outr + (size_t)t * Hn + cb1);
  }
}

// ---------------------------------------------------------------------------
// Fused fallback (used only if workspace is too small for A).
// ---------------------------------------------------------------------------
__global__ __launch_bounds__(256) void fused_kernel(
    const float* __restrict__ x, const float* __restrict__ M,
    const float* __restrict__ E, const float* __restrict__ Ct,
    const float* __restrict__ gamma, const float* __restrict__ beta,
    float* __restrict__ out) {
  const int bn = blockIdx.x;
  const int n = bn & (Nn - 1);
  __shared__ float xs[Tn];
  __shared__ __align__(16) float as[Hn];
  const int tid = threadIdx.x;

  if (tid < Tn) xs[tid] = x[bn * Tn + tid];
  __syncthreads();
  if (tid < Hn) {
    float acc = E[n * Hn + tid];
#pragma unroll 8
    for (int t = 0; t < Tn; ++t) acc = fmaf(xs[t], M[t * Hn + tid], acc);
    as[tid] = acc;
  }
  __syncthreads();

  const int wave = tid >> 6;
  const int lane = tid & 63;
  const int r = lane >> 4;
  const int cg = lane & 15;
  const int cb0 = cg * 4;
  const int cb1 = 64 + cg * 4;

  const float4 a0 = *(const float4*)&as[cb0];
  const float4 a1 = *(const float4*)&as[cb1];
  const float4 g0 = *(const float4*)&gamma[cb0];
  const float4 g1 = *(const float4*)&gamma[cb1];
  const float4 q0 = *(const float4*)&beta[cb0];
  const float4 q1 = *(const float4*)&beta[cb1];

  const int tbase = wave * 4 + r;
  float* outr = out + (size_t)bn * Tn * Hn;
  const float* ct0 = Ct + cb0;
  const float* ct1 = Ct + cb1;

#pragma unroll
  for (int i = 0; i < Tn / 16; ++i) {
    const int t = i * 16 + tbase;
    ln_row_store(a0, a1, g0, g1, q0, q1, ct0 + t * Hn, ct1 + t * Hn,
                 outr + (size_t)t * Hn + cb0, outr + (size_t)t * Hn + cb1);
  }
}

extern "C" void kernel_launch(void* const* d_in, const int* in_sizes, int n_in,
                              void* d_out, int out_size, void* d_ws, size_t ws_size,
                              hipStream_t stream) {
  const float* x        = (const float*)d_in[0];
  const float* Wp       = (const float*)d_in[1];
  const float* bp       = (const float*)d_in[2];
  const float* Wf       = (const float*)d_in[3];
  const float* bf       = (const float*)d_in[4];
  const float* gamma    = (const float*)d_in[5];
  const float* beta     = (const float*)d_in[6];
  const float* node_emb = (const float*)d_in[7];
  const float* time_emb = (const float*)d_in[8];
  float* out = (float*)d_out;

  // Workspace layout (floats): M[96*128] | E[256*128] | Ct[96*128] | A[4096*128]
  float* ws = (float*)d_ws;
  float* M  = ws;
  float* E  = ws + Tn * Hn;
  float* Ct = ws + Tn * Hn + Nn * Hn;
  float* A  = ws + Tn * Hn + Nn * Hn + Tn * Hn;

  const size_t need =
      (size_t)(Tn * Hn + Nn * Hn + Tn * Hn + Bn * Nn * Hn) * sizeof(float);

  precompute_kernel<<<Tn + Nn + Tn, 128, 0, stream>>>(Wp, bp, Wf, bf, node_emb,
                                                      time_emb, M, E, Ct);
  if (ws_size >= need) {
    proj_kernel<<<Bn * Nn / 2, 256, 0, stream>>>(x, M, E, A);
    stream_kernel<<<Bn * Nn, 256, 0, stream>>>(A, Ct, gamma, beta, out);
  } else {
    fused_kernel<<<Bn * Nn, 256, 0, stream>>>(x, M, E, Ct, gamma, beta, out);
  }
}